// Round 9
// baseline (157.262 us; speedup 1.0000x reference)
//
#include <hip/hip_runtime.h>
#include <hip/hip_bf16.h>
#include <math.h>

#define IMG 512
#define TW 64                     // output tile width
#define TH 32                     // output tile height
#define NTX 8                     // 512/64
#define NTY 16                    // 512/32
#define NIMG 48                   // 16*3
#define NBLOCKS (NTX * NTY * NIMG)   // 6144
#define NPIX (16LL * 3 * 512 * 512)

#define C1F 0.0001f
#define C2F 0.0009f

// sbuf: [ch][row 0..47][col 0..87], stride 88 (176 B rows: 16B-aligned b128,
// 44-word lane stride -> 2-way bank aliasing = free). 80 cols staged (20 float4).
#define SR 88
// tbuf: [ch][outcol 0..63][row 0..55], stride 56 (112 B: 16B-aligned, 28-word
// lane stride -> 2-way = free). Rows 0..47 used.
#define TR 56

typedef __attribute__((ext_vector_type(8))) short short8;
typedef __attribute__((ext_vector_type(4))) float float4v;

// Gaussian window (sigma=1.5, ws=11), normalized (double-derived literals).
#define GW0 0.00102838f
#define GW1 0.00759877f
#define GW2 0.03600077f
#define GW3 0.10936069f
#define GW4 0.21300539f
#define GW5 0.26601172f

__device__ __forceinline__ unsigned short f2bf(float f) {
    unsigned u = __builtin_bit_cast(unsigned, f);
    u += 0x7FFF + ((u >> 16) & 1);            // RNE
    return (unsigned short)(u >> 16);
}
__device__ __forceinline__ unsigned pk2(float a, float b) {
    __hip_bfloat162 h = __float22bfloat162_rn(make_float2(a, b));
    unsigned u;
    __builtin_memcpy(&u, &h, 4);
    return u;
}

__global__ __launch_bounds__(256, 3)
void ssim_tile_kernel(const float* __restrict__ xg, const float* __restrict__ yg,
                      float* __restrict__ partials) {
    __shared__ unsigned short sbuf[2][48][SR];   // 16896 B (x, y bf16)
    __shared__ unsigned short tbuf[5][TW][TR];   // 35840 B (h-result, transposed)
    __shared__ unsigned short gwtbl[16];         // bf16 taps, [11..15]=0
    __shared__ float red[8];                     // total ~52.8 KB -> 3 blocks/CU

    const int tid  = threadIdx.x;
    const int lane = tid & 63;
    const int w    = tid >> 6;        // wave 0..3
    const int q    = lane >> 4;       // quad 0..3
    const int n16  = lane & 15;

    const int img = blockIdx.z;
    const int r00  = blockIdx.y * TH - 5;   // global row of staged row 0 (42 real rows)
    const int c00a = blockIdx.x * TW - 8;   // global col of staged col 0 (16B-aligned)
    const float* __restrict__ xi = xg + (size_t)img * (IMG * IMG);
    const float* __restrict__ yi = yg + (size_t)img * (IMG * IMG);

    // ---- bf16 Gaussian tap table (compile-time-folded constants) ----
    if (tid < 16) {
        const float gwf[11] = {GW0, GW1, GW2, GW3, GW4, GW5, GW4, GW3, GW2, GW1, GW0};
        unsigned short v = 0;
        #pragma unroll
        for (int t = 0; t < 11; ++t)
            if (tid == t) v = f2bf(gwf[t]);
        gwtbl[tid] = v;
    }

    // ---- Stage x,y as bf16: 48 rows x 20 float4 = 960 units ----
    // OOB is always whole-float4 (512 % 4 == 0, aligned base): one predicated path.
    for (int u = tid; u < 960; u += 256) {
        int pr  = u / 20;               // 0..47
        int pc4 = (u - pr * 20) << 2;   // 0,4,...,76
        int gr = r00 + pr, gc = c00a + pc4;
        float4 xv = make_float4(0.f, 0.f, 0.f, 0.f);
        float4 yv = make_float4(0.f, 0.f, 0.f, 0.f);
        if (pr < 42 && (unsigned)gr < 512u && (unsigned)gc < 512u) {
            size_t o = (size_t)gr * IMG + gc;
            xv = *(const float4*)(xi + o);
            yv = *(const float4*)(yi + o);
        }
        *(uint2*)&sbuf[0][pr][pc4] = make_uint2(pk2(xv.x, xv.y), pk2(xv.z, xv.w));
        *(uint2*)&sbuf[1][pr][pc4] = make_uint2(pk2(yv.x, yv.y), pk2(yv.z, yv.w));
    }

    // ---- L1 over the 64x32 interior: 8 px/thread, aligned, never OOB, L2-hot ----
    float l1_loc;
    {
        int r  = tid >> 3;              // 0..31
        int c8 = (tid & 7) << 3;        // 0,8,...,56
        size_t o = (size_t)(blockIdx.y * TH + r) * IMG + blockIdx.x * TW + c8;
        float4 a0 = *(const float4*)(xi + o);
        float4 a1 = *(const float4*)(xi + o + 4);
        float4 b0 = *(const float4*)(yi + o);
        float4 b1 = *(const float4*)(yi + o + 4);
        l1_loc = fabsf(a0.x - b0.x) + fabsf(a0.y - b0.y) + fabsf(a0.z - b0.z) + fabsf(a0.w - b0.w)
               + fabsf(a1.x - b1.x) + fabsf(a1.y - b1.y) + fabsf(a1.z - b1.z) + fabsf(a1.w - b1.w);
    }
    __syncthreads();

    // ---- B fragments from LDS table (OOB index -> >=11 -> 0) ----
    // h-conv: out col n reads staged col n+3+t -> Bh[k][n] = g[k-n-3]
    // v-conv: out row n reads hres row n+t     -> Bv[k][n] = g[k-n]
    short8 bh, bv;
    {
        int baseh = q * 8 - n16 - 3;
        int basev = q * 8 - n16;
        #pragma unroll
        for (int j = 0; j < 8; ++j) {
            unsigned ih = min((unsigned)(baseh + j), 15u);
            unsigned iv = min((unsigned)(basev + j), 15u);
            bh[j] = (short)gwtbl[ih];
            bv[j] = (short)gwtbl[iv];
        }
    }

    // ---- H-conv via MFMA: 3 rowgroups x 4 colgroups = 12 units, 3/wave ----
    #pragma unroll
    for (int i = 0; i < 3; ++i) {
        int u = w + i * 4;
        int rg = u >> 2, cg = u & 3;
        short8 ax = *(const short8*)&sbuf[0][rg * 16 + n16][cg * 16 + q * 8];
        short8 ay = *(const short8*)&sbuf[1][rg * 16 + n16][cg * 16 + q * 8];
        short8 axx, ayy, axy;
        {
            unsigned* px = (unsigned*)&ax;
            unsigned* py = (unsigned*)&ay;
            unsigned* pxx = (unsigned*)&axx;
            unsigned* pyy = (unsigned*)&ayy;
            unsigned* pxy = (unsigned*)&axy;
            #pragma unroll
            for (int r = 0; r < 4; ++r) {
                unsigned rx = px[r], ry = py[r];
                float xlo = __builtin_bit_cast(float, rx << 16);
                float xhi = __builtin_bit_cast(float, rx & 0xFFFF0000u);
                float ylo = __builtin_bit_cast(float, ry << 16);
                float yhi = __builtin_bit_cast(float, ry & 0xFFFF0000u);
                pxx[r] = pk2(xlo * xlo, xhi * xhi);
                pyy[r] = pk2(ylo * ylo, yhi * yhi);
                pxy[r] = pk2(xlo * ylo, xhi * yhi);
            }
        }
        // D: lane holds hres rows rg*16+q*4+reg, out col cg*16+n16 -> transposed store
        float4v d;
        d = __builtin_amdgcn_mfma_f32_16x16x32_bf16(ax, bh, (float4v){0.f,0.f,0.f,0.f}, 0, 0, 0);
        *(uint2*)&tbuf[0][cg * 16 + n16][rg * 16 + q * 4] = make_uint2(pk2(d[0], d[1]), pk2(d[2], d[3]));
        d = __builtin_amdgcn_mfma_f32_16x16x32_bf16(ay, bh, (float4v){0.f,0.f,0.f,0.f}, 0, 0, 0);
        *(uint2*)&tbuf[1][cg * 16 + n16][rg * 16 + q * 4] = make_uint2(pk2(d[0], d[1]), pk2(d[2], d[3]));
        d = __builtin_amdgcn_mfma_f32_16x16x32_bf16(axx, bh, (float4v){0.f,0.f,0.f,0.f}, 0, 0, 0);
        *(uint2*)&tbuf[2][cg * 16 + n16][rg * 16 + q * 4] = make_uint2(pk2(d[0], d[1]), pk2(d[2], d[3]));
        d = __builtin_amdgcn_mfma_f32_16x16x32_bf16(ayy, bh, (float4v){0.f,0.f,0.f,0.f}, 0, 0, 0);
        *(uint2*)&tbuf[3][cg * 16 + n16][rg * 16 + q * 4] = make_uint2(pk2(d[0], d[1]), pk2(d[2], d[3]));
        d = __builtin_amdgcn_mfma_f32_16x16x32_bf16(axy, bh, (float4v){0.f,0.f,0.f,0.f}, 0, 0, 0);
        *(uint2*)&tbuf[4][cg * 16 + n16][rg * 16 + q * 4] = make_uint2(pk2(d[0], d[1]), pk2(d[2], d[3]));
    }
    __syncthreads();

    // ---- V-conv via MFMA + SSIM epilogue: wave w = colgroup w, both rowgroups ----
    float ssim_loc = 0.f;
    #pragma unroll
    for (int rgp = 0; rgp < 2; ++rgp) {
        float4v acc5[5];
        #pragma unroll
        for (int ch = 0; ch < 5; ++ch) {
            short8 a = *(const short8*)&tbuf[ch][w * 16 + n16][rgp * 16 + q * 8];
            acc5[ch] = __builtin_amdgcn_mfma_f32_16x16x32_bf16(
                a, bv, (float4v){0.f, 0.f, 0.f, 0.f}, 0, 0, 0);
        }
        #pragma unroll
        for (int r = 0; r < 4; ++r) {
            float mu1 = acc5[0][r], mu2 = acc5[1][r];
            float e11 = acc5[2][r], e22 = acc5[3][r], e12 = acc5[4][r];
            float m1s = mu1 * mu1, m2s = mu2 * mu2, m12 = mu1 * mu2;
            float v1 = e11 - m1s, v2 = e22 - m2s, v12 = e12 - m12;
            float num = (2.f * m12 + C1F) * (2.f * v12 + C2F);
            float den = (m1s + m2s + C1F) * (v1 + v2 + C2F);
            ssim_loc = fmaf(num, __builtin_amdgcn_rcpf(den), ssim_loc);
        }
    }

    // ---- Block reduction ----
    #pragma unroll
    for (int off = 32; off > 0; off >>= 1) {
        ssim_loc += __shfl_down(ssim_loc, off);
        l1_loc   += __shfl_down(l1_loc, off);
    }
    if (lane == 0) {
        red[w] = ssim_loc;
        red[4 + w] = l1_loc;
    }
    __syncthreads();
    if (tid == 0) {
        float ss = red[0] + red[1] + red[2] + red[3];
        float ll = red[4] + red[5] + red[6] + red[7];
        int bid = blockIdx.x + NTX * (blockIdx.y + NTY * blockIdx.z);
        partials[bid] = ss;
        partials[NBLOCKS + bid] = ll;
    }
}

__global__ __launch_bounds__(1024)
void finalize_kernel(const float* __restrict__ partials, float* __restrict__ out) {
    __shared__ double rs[16], rl[16];
    const int tid = threadIdx.x;
    double ss = 0.0, ll = 0.0;
    for (int i = tid; i < NBLOCKS; i += 1024) {
        ss += (double)partials[i];
        ll += (double)partials[NBLOCKS + i];
    }
    #pragma unroll
    for (int off = 32; off > 0; off >>= 1) {
        ss += __shfl_down(ss, off);
        ll += __shfl_down(ll, off);
    }
    int wave = tid >> 6, lane = tid & 63;
    if (lane == 0) { rs[wave] = ss; rl[wave] = ll; }
    __syncthreads();
    if (tid == 0) {
        double sst = 0.0, llt = 0.0;
        #pragma unroll
        for (int w = 0; w < 16; ++w) { sst += rs[w]; llt += rl[w]; }
        double invn = 1.0 / (double)NPIX;
        out[0] = (float)(llt * invn + (1.0 - sst * invn));
    }
}

extern "C" void kernel_launch(void* const* d_in, const int* in_sizes, int n_in,
                              void* d_out, int out_size, void* d_ws, size_t ws_size,
                              hipStream_t stream) {
    const float* x = (const float*)d_in[0];   // outputs
    const float* y = (const float*)d_in[1];   // labels
    float* out = (float*)d_out;
    float* partials = (float*)d_ws;           // 2*NBLOCKS*4 = 49,152 B

    dim3 grid(NTX, NTY, NIMG);
    ssim_tile_kernel<<<grid, dim3(256), 0, stream>>>(x, y, partials);
    finalize_kernel<<<1, dim3(1024), 0, stream>>>(partials, out);
}

// Round 12
// 145.540 us; speedup vs baseline: 1.0805x; 1.0805x over previous
//
#include <hip/hip_runtime.h>
#include <hip/hip_bf16.h>
#include <math.h>

#define IMG 512
#define TW 64                     // output tile width
#define TH 32                     // output tile height
#define NTX 8                     // 512/64
#define NTY 16                    // 512/32
#define NIMG 48                   // 16*3
#define NBLOCKS (NTX * NTY * NIMG)   // 6144
#define NPIX (16LL * 3 * 512 * 512)

#define C1F 0.0001f
#define C2F 0.0009f

// sbuf: [ch][row 0..47][col 0..87], stride 88 elems (176 B rows: 16B-aligned
// b128 reads; 44-word lane stride -> ~2-way bank aliasing). 80 cols staged.
#define SR 88

typedef __attribute__((ext_vector_type(4))) short short4v;
typedef __attribute__((ext_vector_type(8))) short short8;
typedef __attribute__((ext_vector_type(4))) float float4v;
typedef __attribute__((ext_vector_type(2))) unsigned uint2v;

// 16x16x16 bf16 MFMA. Device pass verified to have the _1k builtin on gfx950
// (R11: device compile succeeded, host compile tripped the #else). Host pass
// gets a parse-only stub.
__device__ __forceinline__ float4v mfma16(short4v a, short4v b, float4v c) {
#if defined(__HIP_DEVICE_COMPILE__)
    return __builtin_amdgcn_mfma_f32_16x16x16bf16_1k(a, b, c, 0, 0, 0);
#else
    return c;   // host stub — never executed
#endif
}

// Gaussian window (sigma=1.5, ws=11), normalized (double-derived literals).
#define GW0 0.00102838f
#define GW1 0.00759877f
#define GW2 0.03600077f
#define GW3 0.10936069f
#define GW4 0.21300539f
#define GW5 0.26601172f

__device__ __forceinline__ unsigned short f2bf(float f) {
    unsigned u = __builtin_bit_cast(unsigned, f);
    u += 0x7FFF + ((u >> 16) & 1);            // RNE
    return (unsigned short)(u >> 16);
}
__device__ __forceinline__ unsigned pk2(float a, float b) {
    __hip_bfloat162 h = __float22bfloat162_rn(make_float2(a, b));
    unsigned u;
    __builtin_memcpy(&u, &h, 4);
    return u;
}

__global__ __launch_bounds__(256, 5)
void ssim_tile_kernel(const float* __restrict__ xg, const float* __restrict__ yg,
                      float* __restrict__ partials) {
    __shared__ unsigned short sbuf[2][48][SR];   // 16896 B (x, y bf16) — only big LDS
    __shared__ unsigned short gwtbl[16];         // bf16 taps, [11..15]=0
    __shared__ float red[8];

    const int tid  = threadIdx.x;
    const int lane = tid & 63;
    const int w    = tid >> 6;        // wave 0..3 = colgroup cg
    const int q    = lane >> 4;       // quad 0..3
    const int n16  = lane & 15;

    const int img = blockIdx.z;
    const int r00  = blockIdx.y * TH - 5;   // global row of staged row 0 (42 real)
    const int c00a = blockIdx.x * TW - 8;   // global col of staged col 0 (16B-aligned)
    const float* __restrict__ xi = xg + (size_t)img * (IMG * IMG);
    const float* __restrict__ yi = yg + (size_t)img * (IMG * IMG);

    // ---- bf16 Gaussian tap table (compile-time-folded constants) ----
    if (tid < 16) {
        const float gwf[11] = {GW0, GW1, GW2, GW3, GW4, GW5, GW4, GW3, GW2, GW1, GW0};
        unsigned short v = 0;
        #pragma unroll
        for (int t = 0; t < 11; ++t)
            if (tid == t) v = f2bf(gwf[t]);
        gwtbl[tid] = v;
    }

    // ---- Stage x,y as bf16: 48 rows x 20 float4 (rows 42..47 zero) ----
    for (int u = tid; u < 960; u += 256) {
        int pr  = u / 20;               // 0..47
        int pc4 = (u - pr * 20) << 2;   // 0,4,...,76
        int gr = r00 + pr, gc = c00a + pc4;
        float4 xv = make_float4(0.f, 0.f, 0.f, 0.f);
        float4 yv = make_float4(0.f, 0.f, 0.f, 0.f);
        if (pr < 42 && (unsigned)gr < 512u && (unsigned)gc < 512u) {
            size_t o = (size_t)gr * IMG + gc;
            xv = *(const float4*)(xi + o);
            yv = *(const float4*)(yi + o);
        }
        *(uint2*)&sbuf[0][pr][pc4] = make_uint2(pk2(xv.x, xv.y), pk2(xv.z, xv.w));
        *(uint2*)&sbuf[1][pr][pc4] = make_uint2(pk2(yv.x, yv.y), pk2(yv.z, yv.w));
    }

    // ---- L1 over the 64x32 interior: 8 px/thread, aligned, never OOB ----
    float l1_loc;
    {
        int r  = tid >> 3;              // 0..31
        int c8 = (tid & 7) << 3;        // 0,8,...,56
        size_t o = (size_t)(blockIdx.y * TH + r) * IMG + blockIdx.x * TW + c8;
        float4 a0 = *(const float4*)(xi + o);
        float4 a1 = *(const float4*)(xi + o + 4);
        float4 b0 = *(const float4*)(yi + o);
        float4 b1 = *(const float4*)(yi + o + 4);
        l1_loc = fabsf(a0.x - b0.x) + fabsf(a0.y - b0.y) + fabsf(a0.z - b0.z) + fabsf(a0.w - b0.w)
               + fabsf(a1.x - b1.x) + fabsf(a1.y - b1.y) + fabsf(a1.z - b1.z) + fabsf(a1.w - b1.w);
    }
    __syncthreads();   // the ONLY staging barrier

    // ---- B fragments from gwtbl (OOB index clamps to >=11 -> 0) ----
    // h (K=32): Bh[k][n] = g[k-n-3], k = q*8+j
    // v chunk0 (K=16): Bv0[k][n] = g[k-n], k = q*4+j
    // v chunk1 (K=16): Bv1[k][n] = g[k+16-n]
    short8 bh;
    short4v bv0, bv1;
    {
        int baseh = q * 8 - n16 - 3;
        #pragma unroll
        for (int j = 0; j < 8; ++j)
            bh[j] = (short)gwtbl[min((unsigned)(baseh + j), 15u)];
        int base0 = q * 4 - n16, base1 = q * 4 + 16 - n16;
        #pragma unroll
        for (int j = 0; j < 4; ++j) {
            bv0[j] = (short)gwtbl[min((unsigned)(base0 + j), 15u)];
            bv1[j] = (short)gwtbl[min((unsigned)(base1 + j), 15u)];
        }
    }

    // ---- H-conv via MFMA x32: wave w = colgroup, rg = 0..2, 5 channels.
    //      D1 kept in registers, packed bf16: lane (q,n16) holds hres rows
    //      rg*16+q*4+{0..3} at outcol w*16+n16 — which IS the A-layout of
    //      the 16x16x16 MFMA (m=lane&15, k=quad*4+j). No LDS round-trip. ----
    const float4v zero4 = {0.f, 0.f, 0.f, 0.f};
    uint2v d1[3][5];
    #pragma unroll
    for (int rg = 0; rg < 3; ++rg) {
        short8 ax = *(const short8*)&sbuf[0][rg * 16 + n16][w * 16 + q * 8];
        short8 ay = *(const short8*)&sbuf[1][rg * 16 + n16][w * 16 + q * 8];
        short8 axx, ayy, axy;
        {
            unsigned* px = (unsigned*)&ax;
            unsigned* py = (unsigned*)&ay;
            unsigned* pxx = (unsigned*)&axx;
            unsigned* pyy = (unsigned*)&ayy;
            unsigned* pxy = (unsigned*)&axy;
            #pragma unroll
            for (int r = 0; r < 4; ++r) {
                unsigned rx = px[r], ry = py[r];
                float xlo = __builtin_bit_cast(float, rx << 16);
                float xhi = __builtin_bit_cast(float, rx & 0xFFFF0000u);
                float ylo = __builtin_bit_cast(float, ry << 16);
                float yhi = __builtin_bit_cast(float, ry & 0xFFFF0000u);
                pxx[r] = pk2(xlo * xlo, xhi * xhi);
                pyy[r] = pk2(ylo * ylo, yhi * yhi);
                pxy[r] = pk2(xlo * ylo, xhi * yhi);
            }
        }
        float4v d;
        d = __builtin_amdgcn_mfma_f32_16x16x32_bf16(ax, bh, zero4, 0, 0, 0);
        d1[rg][0] = (uint2v){pk2(d[0], d[1]), pk2(d[2], d[3])};
        d = __builtin_amdgcn_mfma_f32_16x16x32_bf16(ay, bh, zero4, 0, 0, 0);
        d1[rg][1] = (uint2v){pk2(d[0], d[1]), pk2(d[2], d[3])};
        d = __builtin_amdgcn_mfma_f32_16x16x32_bf16(axx, bh, zero4, 0, 0, 0);
        d1[rg][2] = (uint2v){pk2(d[0], d[1]), pk2(d[2], d[3])};
        d = __builtin_amdgcn_mfma_f32_16x16x32_bf16(ayy, bh, zero4, 0, 0, 0);
        d1[rg][3] = (uint2v){pk2(d[0], d[1]), pk2(d[2], d[3])};
        d = __builtin_amdgcn_mfma_f32_16x16x32_bf16(axy, bh, zero4, 0, 0, 0);
        d1[rg][4] = (uint2v){pk2(d[0], d[1]), pk2(d[2], d[3])};
    }

    // ---- V-conv: acc = D1[rgp]·Bv0 + D1[rgp+1]·Bv1 (two chained x16 MFMAs).
    //      D output: lane (q,n16) = out row rgp*16+n16, out cols w*16+q*4+r. ----
    float ssim_loc = 0.f;
    #pragma unroll
    for (int rgp = 0; rgp < 2; ++rgp) {
        float4v acc5[5];
        #pragma unroll
        for (int ch = 0; ch < 5; ++ch) {
            short4v a1 = __builtin_bit_cast(short4v, d1[rgp + 1][ch]);
            short4v a0 = __builtin_bit_cast(short4v, d1[rgp][ch]);
            acc5[ch] = mfma16(a0, bv0, mfma16(a1, bv1, zero4));
        }
        #pragma unroll
        for (int r = 0; r < 4; ++r) {
            float mu1 = acc5[0][r], mu2 = acc5[1][r];
            float e11 = acc5[2][r], e22 = acc5[3][r], e12 = acc5[4][r];
            float m1s = mu1 * mu1, m2s = mu2 * mu2, m12 = mu1 * mu2;
            float v1 = e11 - m1s, v2 = e22 - m2s, v12 = e12 - m12;
            float num = (2.f * m12 + C1F) * (2.f * v12 + C2F);
            float den = (m1s + m2s + C1F) * (v1 + v2 + C2F);
            ssim_loc = fmaf(num, __builtin_amdgcn_rcpf(den), ssim_loc);
        }
    }

    // ---- Block reduction ----
    #pragma unroll
    for (int off = 32; off > 0; off >>= 1) {
        ssim_loc += __shfl_down(ssim_loc, off);
        l1_loc   += __shfl_down(l1_loc, off);
    }
    if (lane == 0) {
        red[w] = ssim_loc;
        red[4 + w] = l1_loc;
    }
    __syncthreads();
    if (tid == 0) {
        float ss = red[0] + red[1] + red[2] + red[3];
        float ll = red[4] + red[5] + red[6] + red[7];
        int bid = blockIdx.x + NTX * (blockIdx.y + NTY * blockIdx.z);
        partials[bid] = ss;
        partials[NBLOCKS + bid] = ll;
    }
}

__global__ __launch_bounds__(1024)
void finalize_kernel(const float* __restrict__ partials, float* __restrict__ out) {
    __shared__ double rs[16], rl[16];
    const int tid = threadIdx.x;
    double ss = 0.0, ll = 0.0;
    for (int i = tid; i < NBLOCKS; i += 1024) {
        ss += (double)partials[i];
        ll += (double)partials[NBLOCKS + i];
    }
    #pragma unroll
    for (int off = 32; off > 0; off >>= 1) {
        ss += __shfl_down(ss, off);
        ll += __shfl_down(ll, off);
    }
    int wave = tid >> 6, lane = tid & 63;
    if (lane == 0) { rs[wave] = ss; rl[wave] = ll; }
    __syncthreads();
    if (tid == 0) {
        double sst = 0.0, llt = 0.0;
        #pragma unroll
        for (int w = 0; w < 16; ++w) { sst += rs[w]; llt += rl[w]; }
        double invn = 1.0 / (double)NPIX;
        out[0] = (float)(llt * invn + (1.0 - sst * invn));
    }
}

extern "C" void kernel_launch(void* const* d_in, const int* in_sizes, int n_in,
                              void* d_out, int out_size, void* d_ws, size_t ws_size,
                              hipStream_t stream) {
    const float* x = (const float*)d_in[0];   // outputs
    const float* y = (const float*)d_in[1];   // labels
    float* out = (float*)d_out;
    float* partials = (float*)d_ws;           // 2*NBLOCKS*4 = 49,152 B

    dim3 grid(NTX, NTY, NIMG);
    ssim_tile_kernel<<<grid, dim3(256), 0, stream>>>(x, y, partials);
    finalize_kernel<<<1, dim3(1024), 0, stream>>>(partials, out);
}

// Round 13
// 139.955 us; speedup vs baseline: 1.1237x; 1.0399x over previous
//
#include <hip/hip_runtime.h>
#include <hip/hip_bf16.h>
#include <math.h>

#define IMG 512
#define TW 64                     // output tile width
#define TH 32                     // output tile height
#define NTX 8                     // 512/64
#define NTY 16                    // 512/32
#define NIMG 48                   // 16*3
#define NBLOCKS (NTX * NTY * NIMG)   // 6144
#define NPIX (16LL * 3 * 512 * 512)

#define C1F 0.0001f
#define C2F 0.0009f

// sbuf: [ch][row 0..47][col 0..87], stride 88 elems (176 B rows: 16B-aligned
// b128 reads; 44-word lane stride -> ~2-way bank aliasing). 80 cols staged.
#define SR 88

typedef __attribute__((ext_vector_type(4))) short short4v;
typedef __attribute__((ext_vector_type(8))) short short8;
typedef __attribute__((ext_vector_type(4))) float float4v;
typedef __attribute__((ext_vector_type(2))) unsigned uint2v;

// 16x16x16 bf16 MFMA (device-verified _1k builtin on gfx950; host parse stub).
__device__ __forceinline__ float4v mfma16(short4v a, short4v b, float4v c) {
#if defined(__HIP_DEVICE_COMPILE__)
    return __builtin_amdgcn_mfma_f32_16x16x16bf16_1k(a, b, c, 0, 0, 0);
#else
    return c;   // host stub — never executed
#endif
}

// Gaussian window (sigma=1.5, ws=11), normalized (double-derived literals).
#define GW0 0.00102838f
#define GW1 0.00759877f
#define GW2 0.03600077f
#define GW3 0.10936069f
#define GW4 0.21300539f
#define GW5 0.26601172f

__device__ __forceinline__ unsigned short f2bf(float f) {
    unsigned u = __builtin_bit_cast(unsigned, f);
    u += 0x7FFF + ((u >> 16) & 1);            // RNE
    return (unsigned short)(u >> 16);
}
__device__ __forceinline__ unsigned pk2(float a, float b) {
    __hip_bfloat162 h = __float22bfloat162_rn(make_float2(a, b));
    unsigned u;
    __builtin_memcpy(&u, &h, 4);
    return u;
}

__global__ __launch_bounds__(256, 5)
void ssim_tile_kernel(const float* __restrict__ xg, const float* __restrict__ yg,
                      float* __restrict__ partials) {
    __shared__ unsigned short sbuf[2][48][SR];   // 16896 B (x, y bf16) — only big LDS
    __shared__ unsigned short gwtbl[16];         // bf16 taps, [11..15]=0
    __shared__ float red[8];

    const int tid  = threadIdx.x;
    const int lane = tid & 63;
    const int w    = tid >> 6;        // wave 0..3 = colgroup cg
    const int q    = lane >> 4;       // quad 0..3
    const int n16  = lane & 15;

    const int img = blockIdx.z;
    const int r00  = blockIdx.y * TH - 5;   // global row of staged row 0 (42 real)
    const int c00a = blockIdx.x * TW - 8;   // global col of staged col 0 (16B-aligned)
    const float* __restrict__ xi = xg + (size_t)img * (IMG * IMG);
    const float* __restrict__ yi = yg + (size_t)img * (IMG * IMG);

    // ---- bf16 Gaussian tap table (compile-time-folded constants) ----
    if (tid < 16) {
        const float gwf[11] = {GW0, GW1, GW2, GW3, GW4, GW5, GW4, GW3, GW2, GW1, GW0};
        unsigned short v = 0;
        #pragma unroll
        for (int t = 0; t < 11; ++t)
            if (tid == t) v = f2bf(gwf[t]);
        gwtbl[tid] = v;
    }

    // ---- Stage x,y as bf16 (48 rows x 20 float4; rows 42..47 zero) with the
    //      L1 sum FOLDED IN: interior float4s (pr in [5,36], pc4 in [8,68])
    //      are never OOB, even at image edges, and tile the 64x32 interior
    //      exactly once -> no separate global re-read (saves ~25 MB HBM). ----
    float l1_loc = 0.f;
    #pragma unroll
    for (int it = 0; it < 4; ++it) {
        int u = tid + it * 256;
        if (it < 3 || tid < 192) {           // 960 units total
            int pr  = u / 20;                // 0..47
            int pc4 = (u - pr * 20) << 2;    // 0,4,...,76
            int gr = r00 + pr, gc = c00a + pc4;
            float4 xv = make_float4(0.f, 0.f, 0.f, 0.f);
            float4 yv = make_float4(0.f, 0.f, 0.f, 0.f);
            if (pr < 42 && (unsigned)gr < 512u && (unsigned)gc < 512u) {
                size_t o = (size_t)gr * IMG + gc;
                xv = *(const float4*)(xi + o);
                yv = *(const float4*)(yi + o);
            }
            *(uint2*)&sbuf[0][pr][pc4] = make_uint2(pk2(xv.x, xv.y), pk2(xv.z, xv.w));
            *(uint2*)&sbuf[1][pr][pc4] = make_uint2(pk2(yv.x, yv.y), pk2(yv.z, yv.w));
            if ((unsigned)(pr - 5) <= 31u && (unsigned)(pc4 - 8) <= 60u)
                l1_loc += fabsf(xv.x - yv.x) + fabsf(xv.y - yv.y)
                        + fabsf(xv.z - yv.z) + fabsf(xv.w - yv.w);
        }
    }
    __syncthreads();   // the ONLY staging barrier

    // ---- B fragments from gwtbl (OOB index clamps to >=11 -> 0) ----
    // h (K=32): Bh[k][n] = g[k-n-3], k = q*8+j
    // v chunk0 (K=16): Bv0[k][n] = g[k-n]; chunk1: Bv1[k][n] = g[k+16-n]
    short8 bh;
    short4v bv0, bv1;
    {
        int baseh = q * 8 - n16 - 3;
        #pragma unroll
        for (int j = 0; j < 8; ++j)
            bh[j] = (short)gwtbl[min((unsigned)(baseh + j), 15u)];
        int base0 = q * 4 - n16, base1 = q * 4 + 16 - n16;
        #pragma unroll
        for (int j = 0; j < 4; ++j) {
            bv0[j] = (short)gwtbl[min((unsigned)(base0 + j), 15u)];
            bv1[j] = (short)gwtbl[min((unsigned)(base1 + j), 15u)];
        }
    }

    // ---- H-conv via MFMA: wave w = colgroup, rg = 0..2, 5 channels.
    //      D1 kept in registers, packed bf16: lane (q,n16) holds hres rows
    //      rg*16+q*4+{0..3} at outcol w*16+n16 — which IS the A-layout of
    //      the 16x16x16 MFMA (m=lane&15, k=quad*4+j). No LDS round-trip. ----
    const float4v zero4 = {0.f, 0.f, 0.f, 0.f};
    uint2v d1[3][5];
    #pragma unroll
    for (int rg = 0; rg < 3; ++rg) {
        short8 ax = *(const short8*)&sbuf[0][rg * 16 + n16][w * 16 + q * 8];
        short8 ay = *(const short8*)&sbuf[1][rg * 16 + n16][w * 16 + q * 8];
        short8 axx, ayy, axy;
        {
            unsigned* px = (unsigned*)&ax;
            unsigned* py = (unsigned*)&ay;
            unsigned* pxx = (unsigned*)&axx;
            unsigned* pyy = (unsigned*)&ayy;
            unsigned* pxy = (unsigned*)&axy;
            #pragma unroll
            for (int r = 0; r < 4; ++r) {
                unsigned rx = px[r], ry = py[r];
                float xlo = __builtin_bit_cast(float, rx << 16);
                float xhi = __builtin_bit_cast(float, rx & 0xFFFF0000u);
                float ylo = __builtin_bit_cast(float, ry << 16);
                float yhi = __builtin_bit_cast(float, ry & 0xFFFF0000u);
                pxx[r] = pk2(xlo * xlo, xhi * xhi);
                pyy[r] = pk2(ylo * ylo, yhi * yhi);
                pxy[r] = pk2(xlo * ylo, xhi * yhi);
            }
        }
        float4v d;
        d = __builtin_amdgcn_mfma_f32_16x16x32_bf16(ax, bh, zero4, 0, 0, 0);
        d1[rg][0] = (uint2v){pk2(d[0], d[1]), pk2(d[2], d[3])};
        d = __builtin_amdgcn_mfma_f32_16x16x32_bf16(ay, bh, zero4, 0, 0, 0);
        d1[rg][1] = (uint2v){pk2(d[0], d[1]), pk2(d[2], d[3])};
        d = __builtin_amdgcn_mfma_f32_16x16x32_bf16(axx, bh, zero4, 0, 0, 0);
        d1[rg][2] = (uint2v){pk2(d[0], d[1]), pk2(d[2], d[3])};
        d = __builtin_amdgcn_mfma_f32_16x16x32_bf16(ayy, bh, zero4, 0, 0, 0);
        d1[rg][3] = (uint2v){pk2(d[0], d[1]), pk2(d[2], d[3])};
        d = __builtin_amdgcn_mfma_f32_16x16x32_bf16(axy, bh, zero4, 0, 0, 0);
        d1[rg][4] = (uint2v){pk2(d[0], d[1]), pk2(d[2], d[3])};
    }

    // ---- V-conv: acc = D1[rgp]·Bv0 + D1[rgp+1]·Bv1 (two chained x16 MFMAs).
    //      D output: lane (q,n16) = out row rgp*16+n16, out cols w*16+q*4+r. ----
    float ssim_loc = 0.f;
    #pragma unroll
    for (int rgp = 0; rgp < 2; ++rgp) {
        float4v acc5[5];
        #pragma unroll
        for (int ch = 0; ch < 5; ++ch) {
            short4v a1 = __builtin_bit_cast(short4v, d1[rgp + 1][ch]);
            short4v a0 = __builtin_bit_cast(short4v, d1[rgp][ch]);
            acc5[ch] = mfma16(a0, bv0, mfma16(a1, bv1, zero4));
        }
        // SSIM, refactored: p=mu1*mu2, s=mu1^2+mu2^2, e=e11+e22
        //   num1=2p+C1, num2=2(e12-p)+C2, den1=s+C1, den2=(e-s)+C2
        #pragma unroll
        for (int r = 0; r < 4; ++r) {
            float mu1 = acc5[0][r], mu2 = acc5[1][r];
            float e11 = acc5[2][r], e22 = acc5[3][r], e12 = acc5[4][r];
            float p = mu1 * mu2;
            float s = fmaf(mu1, mu1, mu2 * mu2);
            float e = e11 + e22;
            float num1 = fmaf(2.f, p, C1F);
            float num2 = fmaf(2.f, e12 - p, C2F);
            float den1 = s + C1F;
            float den2 = (e - s) + C2F;
            ssim_loc = fmaf(num1 * num2, __builtin_amdgcn_rcpf(den1 * den2), ssim_loc);
        }
    }

    // ---- Block reduction ----
    #pragma unroll
    for (int off = 32; off > 0; off >>= 1) {
        ssim_loc += __shfl_down(ssim_loc, off);
        l1_loc   += __shfl_down(l1_loc, off);
    }
    if (lane == 0) {
        red[w] = ssim_loc;
        red[4 + w] = l1_loc;
    }
    __syncthreads();
    if (tid == 0) {
        float ss = red[0] + red[1] + red[2] + red[3];
        float ll = red[4] + red[5] + red[6] + red[7];
        int bid = blockIdx.x + NTX * (blockIdx.y + NTY * blockIdx.z);
        partials[bid] = ss;
        partials[NBLOCKS + bid] = ll;
    }
}

__global__ __launch_bounds__(1024)
void finalize_kernel(const float* __restrict__ partials, float* __restrict__ out) {
    __shared__ double rs[16], rl[16];
    const int tid = threadIdx.x;
    double ss = 0.0, ll = 0.0;
    for (int i = tid; i < NBLOCKS; i += 1024) {
        ss += (double)partials[i];
        ll += (double)partials[NBLOCKS + i];
    }
    #pragma unroll
    for (int off = 32; off > 0; off >>= 1) {
        ss += __shfl_down(ss, off);
        ll += __shfl_down(ll, off);
    }
    int wave = tid >> 6, lane = tid & 63;
    if (lane == 0) { rs[wave] = ss; rl[wave] = ll; }
    __syncthreads();
    if (tid == 0) {
        double sst = 0.0, llt = 0.0;
        #pragma unroll
        for (int w = 0; w < 16; ++w) { sst += rs[w]; llt += rl[w]; }
        double invn = 1.0 / (double)NPIX;
        out[0] = (float)(llt * invn + (1.0 - sst * invn));
    }
}

extern "C" void kernel_launch(void* const* d_in, const int* in_sizes, int n_in,
                              void* d_out, int out_size, void* d_ws, size_t ws_size,
                              hipStream_t stream) {
    const float* x = (const float*)d_in[0];   // outputs
    const float* y = (const float*)d_in[1];   // labels
    float* out = (float*)d_out;
    float* partials = (float*)d_ws;           // 2*NBLOCKS*4 = 49,152 B

    dim3 grid(NTX, NTY, NIMG);
    ssim_tile_kernel<<<grid, dim3(256), 0, stream>>>(x, y, partials);
    finalize_kernel<<<1, dim3(1024), 0, stream>>>(partials, out);
}

// Round 14
// 135.676 us; speedup vs baseline: 1.1591x; 1.0315x over previous
//
#include <hip/hip_runtime.h>
#include <hip/hip_bf16.h>
#include <math.h>

#define IMG 512
#define TW 64                     // output tile width
#define TH 32                     // output tile height
#define NTX 8                     // 512/64
#define NTY 16                    // 512/32
#define NIMG 48                   // 16*3
#define NBLOCKS (NTX * NTY * NIMG)   // 6144
#define NPIX (16LL * 3 * 512 * 512)

#define C1F 0.0001f
#define C2F 0.0009f

// sbuf: [ch][row 0..41][col 0..87], stride 88 shorts (176 B rows: 16B-aligned
// b128; 44-word lane stride -> 2-way bank aliasing = free). 80 cols staged.
// Only 42 rows: hres rows 42..47 have zero v-taps (g[k-n], k-n>=11 -> 0), so
// rg=2 reads clamp to row 41 and the garbage is annihilated by the zero taps.
#define SROWS 42
#define SR 88

typedef __attribute__((ext_vector_type(4))) short short4v;
typedef __attribute__((ext_vector_type(8))) short short8;
typedef __attribute__((ext_vector_type(4))) float float4v;
typedef __attribute__((ext_vector_type(2))) unsigned uint2v;
typedef __attribute__((ext_vector_type(4))) unsigned uint4v;

// 16x16x16 bf16 MFMA (device-verified _1k builtin on gfx950; host parse stub).
__device__ __forceinline__ float4v mfma16(short4v a, short4v b, float4v c) {
#if defined(__HIP_DEVICE_COMPILE__)
    return __builtin_amdgcn_mfma_f32_16x16x16bf16_1k(a, b, c, 0, 0, 0);
#else
    return c;   // host stub — never executed
#endif
}

// Gaussian window (sigma=1.5, ws=11), normalized (double-derived literals).
#define GW0 0.00102838f
#define GW1 0.00759877f
#define GW2 0.03600077f
#define GW3 0.10936069f
#define GW4 0.21300539f
#define GW5 0.26601172f

__device__ __forceinline__ unsigned short f2bf(float f) {
    unsigned u = __builtin_bit_cast(unsigned, f);
    u += 0x7FFF + ((u >> 16) & 1);            // RNE
    return (unsigned short)(u >> 16);
}
__device__ __forceinline__ unsigned pk2(float a, float b) {
    __hip_bfloat162 h = __float22bfloat162_rn(make_float2(a, b));
    unsigned u;
    __builtin_memcpy(&u, &h, 4);
    return u;
}

__global__ __launch_bounds__(256, 4)
void ssim_tile_kernel(const float* __restrict__ xg, const float* __restrict__ yg,
                      float* __restrict__ partials) {
    // ch: 0=x 1=y 2=xx 3=yy 4=xy — products computed ONCE at staging.
    __shared__ unsigned short sbuf[5][SROWS][SR];   // 36960 B -> 4 blocks/CU
    __shared__ unsigned short gwtbl[16];            // bf16 taps, [11..15]=0
    __shared__ float red[8];

    const int tid  = threadIdx.x;
    const int lane = tid & 63;
    const int w    = tid >> 6;        // wave 0..3 = colgroup cg
    const int q    = lane >> 4;       // quad 0..3
    const int n16  = lane & 15;

    const int img = blockIdx.z;
    const int r00  = blockIdx.y * TH - 5;   // global row of staged row 0
    const int c00a = blockIdx.x * TW - 8;   // global col of staged col 0 (16B-aligned)
    const float* __restrict__ xi = xg + (size_t)img * (IMG * IMG);
    const float* __restrict__ yi = yg + (size_t)img * (IMG * IMG);

    // ---- bf16 Gaussian tap table (compile-time-folded constants) ----
    if (tid < 16) {
        const float gwf[11] = {GW0, GW1, GW2, GW3, GW4, GW5, GW4, GW3, GW2, GW1, GW0};
        unsigned short v = 0;
        #pragma unroll
        for (int t = 0; t < 11; ++t)
            if (tid == t) v = f2bf(gwf[t]);
        gwtbl[tid] = v;
    }

    // ---- Stage 5 bf16 channels, 42 rows x 10 groups-of-8-cols = 420 units.
    //      OOB is whole-float4 (512%4==0, aligned base): 2 predicates/unit.
    //      L1 folded in: interior units (pr in [5,36], g10 in [1,8]) tile the
    //      64x32 interior exactly once and are never OOB. ----
    float l1_loc = 0.f;
    #pragma unroll
    for (int it = 0; it < 2; ++it) {
        int u = tid + it * 256;
        if (it == 0 || tid < 420 - 256) {
            int pr  = u / 10;               // 0..41
            int g10 = u - pr * 10;          // 0..9
            int pc8 = g10 << 3;             // 0,8,...,72
            int gr = r00 + pr, gc = c00a + pc8;
            float4 x0 = make_float4(0.f, 0.f, 0.f, 0.f), x1 = x0;
            float4 y0 = x0, y1 = x0;
            bool rowok = (unsigned)gr < 512u;
            size_t o = (size_t)gr * IMG + gc;
            if (rowok && (unsigned)gc < 512u) {
                x0 = *(const float4*)(xi + o);
                y0 = *(const float4*)(yi + o);
            }
            if (rowok && (unsigned)(gc + 4) < 512u) {
                x1 = *(const float4*)(xi + o + 4);
                y1 = *(const float4*)(yi + o + 4);
            }
            *(uint4v*)&sbuf[0][pr][pc8] = (uint4v){
                pk2(x0.x, x0.y), pk2(x0.z, x0.w), pk2(x1.x, x1.y), pk2(x1.z, x1.w)};
            *(uint4v*)&sbuf[1][pr][pc8] = (uint4v){
                pk2(y0.x, y0.y), pk2(y0.z, y0.w), pk2(y1.x, y1.y), pk2(y1.z, y1.w)};
            *(uint4v*)&sbuf[2][pr][pc8] = (uint4v){
                pk2(x0.x * x0.x, x0.y * x0.y), pk2(x0.z * x0.z, x0.w * x0.w),
                pk2(x1.x * x1.x, x1.y * x1.y), pk2(x1.z * x1.z, x1.w * x1.w)};
            *(uint4v*)&sbuf[3][pr][pc8] = (uint4v){
                pk2(y0.x * y0.x, y0.y * y0.y), pk2(y0.z * y0.z, y0.w * y0.w),
                pk2(y1.x * y1.x, y1.y * y1.y), pk2(y1.z * y1.z, y1.w * y1.w)};
            *(uint4v*)&sbuf[4][pr][pc8] = (uint4v){
                pk2(x0.x * y0.x, x0.y * y0.y), pk2(x0.z * y0.z, x0.w * y0.w),
                pk2(x1.x * y1.x, x1.y * y1.y), pk2(x1.z * y1.z, x1.w * y1.w)};
            if ((unsigned)(pr - 5) <= 31u && (unsigned)(g10 - 1) <= 7u)
                l1_loc += fabsf(x0.x - y0.x) + fabsf(x0.y - y0.y)
                        + fabsf(x0.z - y0.z) + fabsf(x0.w - y0.w)
                        + fabsf(x1.x - y1.x) + fabsf(x1.y - y1.y)
                        + fabsf(x1.z - y1.z) + fabsf(x1.w - y1.w);
        }
    }
    __syncthreads();   // the ONLY staging barrier

    // ---- B fragments from gwtbl (OOB index clamps to >=11 -> 0) ----
    // h (K=32): Bh[k][n] = g[k-n-3], k = q*8+j
    // v chunk0 (K=16): Bv0[k][n] = g[k-n]; chunk1: Bv1[k][n] = g[k+16-n]
    short8 bh;
    short4v bv0, bv1;
    {
        int baseh = q * 8 - n16 - 3;
        #pragma unroll
        for (int j = 0; j < 8; ++j)
            bh[j] = (short)gwtbl[min((unsigned)(baseh + j), 15u)];
        int base0 = q * 4 - n16, base1 = q * 4 + 16 - n16;
        #pragma unroll
        for (int j = 0; j < 4; ++j) {
            bv0[j] = (short)gwtbl[min((unsigned)(base0 + j), 15u)];
            bv1[j] = (short)gwtbl[min((unsigned)(base1 + j), 15u)];
        }
    }

    // ---- H-conv via MFMA: wave w = colgroup, rg = 0..2, 5 channels read
    //      straight from LDS (no rebuild). rg=2 rows >41 clamp to 41 — their
    //      hres feeds only zero v-taps, so values are don't-care (finite). ----
    const float4v zero4 = {0.f, 0.f, 0.f, 0.f};
    uint2v d1[3][5];
    #pragma unroll
    for (int rg = 0; rg < 3; ++rg) {
        int row = rg * 16 + n16;
        if (rg == 2) row = min(row, 41);
        const int co = w * 16 + q * 8;
        #pragma unroll
        for (int ch = 0; ch < 5; ++ch) {
            short8 a = *(const short8*)&sbuf[ch][row][co];
            float4v d = __builtin_amdgcn_mfma_f32_16x16x32_bf16(a, bh, zero4, 0, 0, 0);
            d1[rg][ch] = (uint2v){pk2(d[0], d[1]), pk2(d[2], d[3])};
        }
    }

    // ---- V-conv: acc = D1[rgp]·Bv0 + D1[rgp+1]·Bv1 (two chained x16 MFMAs).
    //      D output: lane (q,n16) = out row rgp*16+n16, out cols w*16+q*4+r. ----
    float ssim_loc = 0.f;
    #pragma unroll
    for (int rgp = 0; rgp < 2; ++rgp) {
        float4v acc5[5];
        #pragma unroll
        for (int ch = 0; ch < 5; ++ch) {
            short4v a1 = __builtin_bit_cast(short4v, d1[rgp + 1][ch]);
            short4v a0 = __builtin_bit_cast(short4v, d1[rgp][ch]);
            acc5[ch] = mfma16(a0, bv0, mfma16(a1, bv1, zero4));
        }
        // SSIM: p=mu1*mu2, s=mu1^2+mu2^2, e=e11+e22
        #pragma unroll
        for (int r = 0; r < 4; ++r) {
            float mu1 = acc5[0][r], mu2 = acc5[1][r];
            float e11 = acc5[2][r], e22 = acc5[3][r], e12 = acc5[4][r];
            float p = mu1 * mu2;
            float s = fmaf(mu1, mu1, mu2 * mu2);
            float e = e11 + e22;
            float num1 = fmaf(2.f, p, C1F);
            float num2 = fmaf(2.f, e12 - p, C2F);
            float den1 = s + C1F;
            float den2 = (e - s) + C2F;
            ssim_loc = fmaf(num1 * num2, __builtin_amdgcn_rcpf(den1 * den2), ssim_loc);
        }
    }

    // ---- Block reduction ----
    #pragma unroll
    for (int off = 32; off > 0; off >>= 1) {
        ssim_loc += __shfl_down(ssim_loc, off);
        l1_loc   += __shfl_down(l1_loc, off);
    }
    if (lane == 0) {
        red[w] = ssim_loc;
        red[4 + w] = l1_loc;
    }
    __syncthreads();
    if (tid == 0) {
        float ss = red[0] + red[1] + red[2] + red[3];
        float ll = red[4] + red[5] + red[6] + red[7];
        int bid = blockIdx.x + NTX * (blockIdx.y + NTY * blockIdx.z);
        partials[bid] = ss;
        partials[NBLOCKS + bid] = ll;
    }
}

__global__ __launch_bounds__(1024)
void finalize_kernel(const float* __restrict__ partials, float* __restrict__ out) {
    __shared__ double rs[16], rl[16];
    const int tid = threadIdx.x;
    double ss = 0.0, ll = 0.0;
    for (int i = tid; i < NBLOCKS; i += 1024) {
        ss += (double)partials[i];
        ll += (double)partials[NBLOCKS + i];
    }
    #pragma unroll
    for (int off = 32; off > 0; off >>= 1) {
        ss += __shfl_down(ss, off);
        ll += __shfl_down(ll, off);
    }
    int wave = tid >> 6, lane = tid & 63;
    if (lane == 0) { rs[wave] = ss; rl[wave] = ll; }
    __syncthreads();
    if (tid == 0) {
        double sst = 0.0, llt = 0.0;
        #pragma unroll
        for (int w = 0; w < 16; ++w) { sst += rs[w]; llt += rl[w]; }
        double invn = 1.0 / (double)NPIX;
        out[0] = (float)(llt * invn + (1.0 - sst * invn));
    }
}

extern "C" void kernel_launch(void* const* d_in, const int* in_sizes, int n_in,
                              void* d_out, int out_size, void* d_ws, size_t ws_size,
                              hipStream_t stream) {
    const float* x = (const float*)d_in[0];   // outputs
    const float* y = (const float*)d_in[1];   // labels
    float* out = (float*)d_out;
    float* partials = (float*)d_ws;           // 2*NBLOCKS*4 = 49,152 B

    dim3 grid(NTX, NTY, NIMG);
    ssim_tile_kernel<<<grid, dim3(256), 0, stream>>>(x, y, partials);
    finalize_kernel<<<1, dim3(1024), 0, stream>>>(partials, out);
}